// Round 6
// baseline (1993.962 us; speedup 1.0000x reference)
//
#include <hip/hip_runtime.h>

#define NN 100000
#define NE 1600000
#define D 64

// ---------------------------------------------------------------------------
// Kernel 1: edge scatter.  16 threads per edge, float4 per thread (256B/edge).
// agg accumulated into d_out (zeroed beforehand).
// ---------------------------------------------------------------------------
__global__ __launch_bounds__(256) void gine_edge_kernel(
    const float* __restrict__ x,
    const int*   __restrict__ ei,     // [2, NE] int32: first NE = src, next NE = dst
    const float* __restrict__ ea,     // [NE, D]
    float*       __restrict__ agg)    // [NN, D] pre-zeroed
{
    long long tid = (long long)blockIdx.x * blockDim.x + threadIdx.x;
    int edge = (int)(tid >> 4);
    int l    = (int)(tid & 15);       // 16 groups of 4 floats
    if (edge >= NE) return;

    int src = ei[edge];
    int dst = ei[NE + edge];

    const float4 e4 = *(const float4*)(ea + (long long)edge * D + l * 4);
    const float4 x4 = *(const float4*)(x  + (long long)src  * D + l * 4);

    float4 m;
    m.x = fmaxf(x4.x + e4.x, 0.0f);
    m.y = fmaxf(x4.y + e4.y, 0.0f);
    m.z = fmaxf(x4.z + e4.z, 0.0f);
    m.w = fmaxf(x4.w + e4.w, 0.0f);

    float* p = agg + (long long)dst * D + l * 4;
    atomicAdd(p + 0, m.x);
    atomicAdd(p + 1, m.y);
    atomicAdd(p + 2, m.z);
    atomicAdd(p + 3, m.w);
}

// ---------------------------------------------------------------------------
// Kernel 2: per-node MLP.  One wave (64 lanes) per node; lane j owns dim j.
// h broadcast across lanes with __shfl; W1/W2 staged in LDS.
// agg_out aliases d_out: read own row (agg), overwrite with final output.
// ---------------------------------------------------------------------------
__global__ __launch_bounds__(256) void gine_mlp_kernel(
    const float* __restrict__ x,
    const float* __restrict__ W1,
    const float* __restrict__ b1,
    const float* __restrict__ W2,
    const float* __restrict__ b2,
    float*                    agg_out)   // [NN, D]; in: agg, out: result
{
    __shared__ float sW1[D * D];
    __shared__ float sW2[D * D];
    for (int i = threadIdx.x; i < D * D; i += 256) {
        sW1[i] = W1[i];
        sW2[i] = W2[i];
    }
    __syncthreads();

    int wave = threadIdx.x >> 6;
    int lane = threadIdx.x & 63;
    int node = blockIdx.x * 4 + wave;
    if (node >= NN) return;

    long long base = (long long)node * D + lane;
    float h = x[base] + agg_out[base];

    // t = relu(h @ W1 + b1)
    float acc = b1[lane];
    #pragma unroll
    for (int i = 0; i < D; ++i) {
        float v = __shfl(h, i);
        acc = fmaf(v, sW1[i * D + lane], acc);
    }
    float t = fmaxf(acc, 0.0f);

    // out = t @ W2 + b2
    float acc2 = b2[lane];
    #pragma unroll
    for (int i = 0; i < D; ++i) {
        float v = __shfl(t, i);
        acc2 = fmaf(v, sW2[i * D + lane], acc2);
    }

    agg_out[base] = acc2;
}

// ---------------------------------------------------------------------------
extern "C" void kernel_launch(void* const* d_in, const int* in_sizes, int n_in,
                              void* d_out, int out_size, void* d_ws, size_t ws_size,
                              hipStream_t stream)
{
    const float* x  = (const float*)d_in[0];
    const int*   ei = (const int*)  d_in[1];
    const float* ea = (const float*)d_in[2];
    const float* W1 = (const float*)d_in[3];
    const float* b1 = (const float*)d_in[4];
    const float* W2 = (const float*)d_in[5];
    const float* b2 = (const float*)d_in[6];
    float* out = (float*)d_out;

    // zero the aggregation buffer (== d_out)
    hipMemsetAsync(out, 0, (size_t)NN * D * sizeof(float), stream);

    // edge scatter: NE * 16 threads
    {
        long long threads = (long long)NE * 16;
        int block = 256;
        int grid  = (int)((threads + block - 1) / block);
        gine_edge_kernel<<<grid, block, 0, stream>>>(x, ei, ea, out);
    }

    // node MLP: one wave per node, 4 nodes per block
    {
        int block = 256;
        int grid  = (NN + 3) / 4;
        gine_mlp_kernel<<<grid, block, 0, stream>>>(x, W1, b1, W2, b2, out);
    }
}

// Round 9
// 1725.397 us; speedup vs baseline: 1.1557x; 1.1557x over previous
//
#include <hip/hip_runtime.h>

#define NN 100000
#define NE 1600000
#define D 64
#define SCAN_THREADS 1024
#define CHUNK ((NN + SCAN_THREADS - 1) / SCAN_THREADS)   // 98

// ---------------------------------------------------------------------------
// ws layout (ints):  cursor[NN] | offsets[NN+1] | perm[NE]   (~7.2 MB)
// ---------------------------------------------------------------------------

// Kernel 1: histogram of dst degrees (int atomics only).
__global__ __launch_bounds__(256) void hist_kernel(const int* __restrict__ ei,
                                                   int* __restrict__ cnt) {
    int e = blockIdx.x * blockDim.x + threadIdx.x;
    if (e < NE) atomicAdd(&cnt[ei[NE + e]], 1);
}

// Kernel 2: single-block exclusive scan; writes offsets and cursor(=offsets copy).
// cnt and cursor alias the same buffer: each thread reads its own chunk then
// overwrites it, sequentially, so no hazard.
__global__ __launch_bounds__(SCAN_THREADS) void scan_kernel(int* __restrict__ cnt_cursor,
                                                            int* __restrict__ offsets) {
    __shared__ int sums[SCAN_THREADS];
    int tid = threadIdx.x;
    int begin = tid * CHUNK;
    int end   = begin + CHUNK < NN ? begin + CHUNK : NN;
    int s = 0;
    for (int i = begin; i < end; ++i) s += cnt_cursor[i];
    sums[tid] = s;
    __syncthreads();
    // Hillis-Steele inclusive scan over the 1024 chunk sums
    for (int ofs = 1; ofs < SCAN_THREADS; ofs <<= 1) {
        int v = (tid >= ofs) ? sums[tid - ofs] : 0;
        __syncthreads();
        sums[tid] += v;
        __syncthreads();
    }
    int run = (tid == 0) ? 0 : sums[tid - 1];   // exclusive base for this chunk
    for (int i = begin; i < end; ++i) {
        int c = cnt_cursor[i];
        offsets[i]    = run;
        cnt_cursor[i] = run;   // becomes cursor
        run += c;
    }
    if (tid == SCAN_THREADS - 1) offsets[NN] = run;   // == NE
}

// Kernel 3: fill permutation (edge ids grouped by dst).
__global__ __launch_bounds__(256) void fill_kernel(const int* __restrict__ ei,
                                                   int* __restrict__ cursor,
                                                   int* __restrict__ perm) {
    int e = blockIdx.x * blockDim.x + threadIdx.x;
    if (e < NE) {
        int slot = atomicAdd(&cursor[ei[NE + e]], 1);
        perm[slot] = e;
    }
}

// Kernel 4: fused gather-reduce + MLP. One wave per node; lane d owns dim d.
// Weights staged in LDS once per block; block loops over many nodes.
__global__ __launch_bounds__(256) void gather_mlp_kernel(
    const float* __restrict__ x,
    const int*   __restrict__ ei,
    const float* __restrict__ ea,
    const int*   __restrict__ offsets,
    const int*   __restrict__ perm,
    const float* __restrict__ W1,
    const float* __restrict__ b1,
    const float* __restrict__ W2,
    const float* __restrict__ b2,
    float*       __restrict__ out)
{
    __shared__ float sW1[D * D];
    __shared__ float sW2[D * D];
    __shared__ float sh[4][D];
    for (int i = threadIdx.x; i < D * D; i += 256) {
        sW1[i] = W1[i];
        sW2[i] = W2[i];
    }
    __syncthreads();

    int wave = threadIdx.x >> 6;
    int lane = threadIdx.x & 63;
    float rb1 = b1[lane];
    float rb2 = b2[lane];

    for (int n = blockIdx.x * 4 + wave; n < NN; n += gridDim.x * 4) {
        int off = offsets[n];
        int end = offsets[n + 1];

        // gather-reduce: sum relu(x[src] + ea[e]) over incoming edges
        float acc = 0.0f;
        for (int k = off; k < end; ++k) {
            int e   = perm[k];              // wave-uniform
            int src = ei[e];                // wave-uniform
            float m = x[(long long)src * D + lane] + ea[(long long)e * D + lane];
            acc += fmaxf(m, 0.0f);
        }
        float h = x[(long long)n * D + lane] + acc;

        // layer 1: t = relu(h @ W1 + b1); h broadcast via LDS row
        sh[wave][lane] = h;
        float a1 = rb1;
        #pragma unroll
        for (int i = 0; i < D / 4; ++i) {
            float4 hv = *(const float4*)&sh[wave][i * 4];
            a1 = fmaf(hv.x, sW1[(i * 4 + 0) * D + lane], a1);
            a1 = fmaf(hv.y, sW1[(i * 4 + 1) * D + lane], a1);
            a1 = fmaf(hv.z, sW1[(i * 4 + 2) * D + lane], a1);
            a1 = fmaf(hv.w, sW1[(i * 4 + 3) * D + lane], a1);
        }
        float t = fmaxf(a1, 0.0f);

        // layer 2: out = t @ W2 + b2
        sh[wave][lane] = t;   // lockstep wave: all layer-1 reads already issued
        float a2 = rb2;
        #pragma unroll
        for (int i = 0; i < D / 4; ++i) {
            float4 tv = *(const float4*)&sh[wave][i * 4];
            a2 = fmaf(tv.x, sW2[(i * 4 + 0) * D + lane], a2);
            a2 = fmaf(tv.y, sW2[(i * 4 + 1) * D + lane], a2);
            a2 = fmaf(tv.z, sW2[(i * 4 + 2) * D + lane], a2);
            a2 = fmaf(tv.w, sW2[(i * 4 + 3) * D + lane], a2);
        }
        out[(long long)n * D + lane] = a2;
    }
}

// ---------------------------------------------------------------------------
extern "C" void kernel_launch(void* const* d_in, const int* in_sizes, int n_in,
                              void* d_out, int out_size, void* d_ws, size_t ws_size,
                              hipStream_t stream)
{
    const float* x  = (const float*)d_in[0];
    const int*   ei = (const int*)  d_in[1];
    const float* ea = (const float*)d_in[2];
    const float* W1 = (const float*)d_in[3];
    const float* b1 = (const float*)d_in[4];
    const float* W2 = (const float*)d_in[5];
    const float* b2 = (const float*)d_in[6];
    float* out = (float*)d_out;

    int* cursor  = (int*)d_ws;            // [NN]  (cnt, then cursor)
    int* offsets = cursor + NN;           // [NN+1]
    int* perm    = offsets + NN + 1;      // [NE]

    // zero the histogram
    hipMemsetAsync(cursor, 0, (size_t)NN * sizeof(int), stream);

    hist_kernel<<<(NE + 255) / 256, 256, 0, stream>>>(ei, cursor);
    scan_kernel<<<1, SCAN_THREADS, 0, stream>>>(cursor, offsets);
    fill_kernel<<<(NE + 255) / 256, 256, 0, stream>>>(ei, cursor, perm);
    gather_mlp_kernel<<<1024, 256, 0, stream>>>(x, ei, ea, offsets, perm,
                                                W1, b1, W2, b2, out);
}

// Round 11
// 902.716 us; speedup vs baseline: 2.2088x; 1.9113x over previous
//
#include <hip/hip_runtime.h>

#define NN 100000
#define NE 1600000
#define D 64
#define TILE 1024
#define NB ((NN + TILE - 1) / TILE)   // 98 scan tiles

// ---------------------------------------------------------------------------
// ws layout (ints):
//   cnt_cursor[NN] | offsets[NN+1] | bsum[NB] | pad | perm2[NE] (int2)
// total ~13.6 MB
// ---------------------------------------------------------------------------

// Kernel 1: histogram of dst degrees (int atomics).
__global__ __launch_bounds__(256) void hist_kernel(const int* __restrict__ ei,
                                                   int* __restrict__ cnt) {
    int e = blockIdx.x * blockDim.x + threadIdx.x;
    if (e < NE) atomicAdd(&cnt[ei[NE + e]], 1);
}

// Kernel 2a: per-tile sums (tile = 1024 counts).
__global__ __launch_bounds__(256) void scan_sums_kernel(const int* __restrict__ cnt,
                                                        int* __restrict__ bsum) {
    __shared__ int red[256];
    int base = blockIdx.x * TILE + threadIdx.x * 4;
    int s = 0;
    if (base + 3 < NN) {
        int4 v = *(const int4*)(cnt + base);
        s = v.x + v.y + v.z + v.w;
    } else {
        for (int j = 0; j < 4; ++j) if (base + j < NN) s += cnt[base + j];
    }
    red[threadIdx.x] = s;
    __syncthreads();
    for (int o = 128; o > 0; o >>= 1) {
        if (threadIdx.x < o) red[threadIdx.x] += red[threadIdx.x + o];
        __syncthreads();
    }
    if (threadIdx.x == 0) bsum[blockIdx.x] = red[0];
}

// Kernel 2b: exclusive scan of the 98 tile sums (single tiny block).
__global__ __launch_bounds__(128) void scan_bsum_kernel(int* __restrict__ bsum) {
    __shared__ int s[128];
    int t = threadIdx.x;
    s[t] = (t < NB) ? bsum[t] : 0;
    __syncthreads();
    for (int o = 1; o < 128; o <<= 1) {
        int v = (t >= o) ? s[t - o] : 0;
        __syncthreads();
        s[t] += v;
        __syncthreads();
    }
    if (t < NB) bsum[t] = (t == 0) ? 0 : s[t - 1];
}

// Kernel 2c: per-tile exclusive scan + base; writes offsets and cursor(=cnt alias).
__global__ __launch_bounds__(256) void scan_write_kernel(int* __restrict__ cnt_cursor,
                                                         const int* __restrict__ bsum,
                                                         int* __restrict__ offsets) {
    __shared__ int red[256];
    int base = blockIdx.x * TILE + threadIdx.x * 4;
    int c0 = 0, c1 = 0, c2 = 0, c3 = 0;
    if (base + 3 < NN) {
        int4 v = *(const int4*)(cnt_cursor + base);
        c0 = v.x; c1 = v.y; c2 = v.z; c3 = v.w;
    } else {
        if (base     < NN) c0 = cnt_cursor[base];
        if (base + 1 < NN) c1 = cnt_cursor[base + 1];
        if (base + 2 < NN) c2 = cnt_cursor[base + 2];
        if (base + 3 < NN) c3 = cnt_cursor[base + 3];
    }
    red[threadIdx.x] = c0 + c1 + c2 + c3;
    __syncthreads();
    for (int o = 1; o < 256; o <<= 1) {
        int v = (threadIdx.x >= o) ? red[threadIdx.x - o] : 0;
        __syncthreads();
        red[threadIdx.x] += v;
        __syncthreads();
    }
    int p = bsum[blockIdx.x] + ((threadIdx.x == 0) ? 0 : red[threadIdx.x - 1]);
    int o0 = p, o1 = o0 + c0, o2 = o1 + c1, o3 = o2 + c2;
    // each thread writes back only its own 4 slots (cnt/cursor alias is safe)
    if (base     < NN) { offsets[base]     = o0; cnt_cursor[base]     = o0; }
    if (base + 1 < NN) { offsets[base + 1] = o1; cnt_cursor[base + 1] = o1; }
    if (base + 2 < NN) { offsets[base + 2] = o2; cnt_cursor[base + 2] = o2; }
    if (base + 3 < NN) { offsets[base + 3] = o3; cnt_cursor[base + 3] = o3; }
    if (blockIdx.x == 0 && threadIdx.x == 0) offsets[NN] = NE;  // total = NE
}

// Kernel 3: fill permutation with {edge, src} pairs (kills the ei[e] dependent load).
__global__ __launch_bounds__(256) void fill_kernel(const int* __restrict__ ei,
                                                   int* __restrict__ cursor,
                                                   int2* __restrict__ perm2) {
    int e = blockIdx.x * blockDim.x + threadIdx.x;
    if (e < NE) {
        int src = ei[e];
        int dst = ei[NE + e];
        int slot = atomicAdd(&cursor[dst], 1);
        perm2[slot] = make_int2(e, src);
    }
}

// Kernel 4: fused gather-reduce + MLP. One wave per node; lane d owns dim d.
// 8 waves/block; edge loop batched x4 for memory-level parallelism.
__global__ __launch_bounds__(512, 4) void gather_mlp_kernel(
    const float* __restrict__ x,
    const float* __restrict__ ea,
    const int*   __restrict__ offsets,
    const int2*  __restrict__ perm2,
    const float* __restrict__ W1,
    const float* __restrict__ b1,
    const float* __restrict__ W2,
    const float* __restrict__ b2,
    float*       __restrict__ out)
{
    __shared__ float sW1[D * D];
    __shared__ float sW2[D * D];
    __shared__ float sh[8][D];
    for (int i = threadIdx.x; i < D * D; i += 512) {
        sW1[i] = W1[i];
        sW2[i] = W2[i];
    }
    __syncthreads();

    int wave = threadIdx.x >> 6;
    int lane = threadIdx.x & 63;
    float rb1 = b1[lane];
    float rb2 = b2[lane];

    for (int n = blockIdx.x * 8 + wave; n < NN; n += gridDim.x * 8) {
        int off = offsets[n];
        int end = offsets[n + 1];

        float acc = 0.0f;
        int k = off;
        // batched x4: 4 index loads issue together, then 8 independent row loads
        for (; k + 4 <= end; k += 4) {
            int2 p0 = perm2[k];
            int2 p1 = perm2[k + 1];
            int2 p2 = perm2[k + 2];
            int2 p3 = perm2[k + 3];
            float e0 = ea[p0.x * D + lane];
            float e1 = ea[p1.x * D + lane];
            float e2 = ea[p2.x * D + lane];
            float e3 = ea[p3.x * D + lane];
            float x0 = x[p0.y * D + lane];
            float x1 = x[p1.y * D + lane];
            float x2 = x[p2.y * D + lane];
            float x3 = x[p3.y * D + lane];
            acc += fmaxf(x0 + e0, 0.0f);
            acc += fmaxf(x1 + e1, 0.0f);
            acc += fmaxf(x2 + e2, 0.0f);
            acc += fmaxf(x3 + e3, 0.0f);
        }
        for (; k < end; ++k) {
            int2 p = perm2[k];
            acc += fmaxf(x[p.y * D + lane] + ea[p.x * D + lane], 0.0f);
        }
        float h = x[n * D + lane] + acc;

        // layer 1: t = relu(h @ W1 + b1); h broadcast via LDS row
        sh[wave][lane] = h;
        float a1 = rb1;
        #pragma unroll
        for (int i = 0; i < D / 4; ++i) {
            float4 hv = *(const float4*)&sh[wave][i * 4];
            a1 = fmaf(hv.x, sW1[(i * 4 + 0) * D + lane], a1);
            a1 = fmaf(hv.y, sW1[(i * 4 + 1) * D + lane], a1);
            a1 = fmaf(hv.z, sW1[(i * 4 + 2) * D + lane], a1);
            a1 = fmaf(hv.w, sW1[(i * 4 + 3) * D + lane], a1);
        }
        float t = fmaxf(a1, 0.0f);

        // layer 2: out = t @ W2 + b2
        sh[wave][lane] = t;
        float a2 = rb2;
        #pragma unroll
        for (int i = 0; i < D / 4; ++i) {
            float4 tv = *(const float4*)&sh[wave][i * 4];
            a2 = fmaf(tv.x, sW2[(i * 4 + 0) * D + lane], a2);
            a2 = fmaf(tv.y, sW2[(i * 4 + 1) * D + lane], a2);
            a2 = fmaf(tv.z, sW2[(i * 4 + 2) * D + lane], a2);
            a2 = fmaf(tv.w, sW2[(i * 4 + 3) * D + lane], a2);
        }
        out[n * D + lane] = a2;
    }
}

// ---------------------------------------------------------------------------
extern "C" void kernel_launch(void* const* d_in, const int* in_sizes, int n_in,
                              void* d_out, int out_size, void* d_ws, size_t ws_size,
                              hipStream_t stream)
{
    const float* x  = (const float*)d_in[0];
    const int*   ei = (const int*)  d_in[1];
    const float* ea = (const float*)d_in[2];
    const float* W1 = (const float*)d_in[3];
    const float* b1 = (const float*)d_in[4];
    const float* W2 = (const float*)d_in[5];
    const float* b2 = (const float*)d_in[6];
    float* out = (float*)d_out;

    int* cursor  = (int*)d_ws;                 // [NN]  (cnt, then cursor)
    int* offsets = cursor + NN;                // [NN+1]
    int* bsum    = offsets + NN + 1;           // [NB]
    int2* perm2  = (int2*)(bsum + NB + 1);     // [NE], 8B-aligned (200100 ints)

    hipMemsetAsync(cursor, 0, (size_t)NN * sizeof(int), stream);

    hist_kernel      <<<(NE + 255) / 256, 256, 0, stream>>>(ei, cursor);
    scan_sums_kernel <<<NB, 256, 0, stream>>>(cursor, bsum);
    scan_bsum_kernel <<<1, 128, 0, stream>>>(bsum);
    scan_write_kernel<<<NB, 256, 0, stream>>>(cursor, bsum, offsets);
    fill_kernel      <<<(NE + 255) / 256, 256, 0, stream>>>(ei, cursor, perm2);
    gather_mlp_kernel<<<2048, 512, 0, stream>>>(x, ea, offsets, perm2,
                                                W1, b1, W2, b2, out);
}